// Round 1
// 232.385 us; speedup vs baseline: 1.1101x; 1.1101x over previous
//
#include <hip/hip_runtime.h>
#include <hip/hip_bf16.h>

#define B_ 8
#define G_ 256
#define N_ 1024
#define P_ 4
#define F_ 256
#define KHOP 4
#define KG_ (KHOP * G_)   // 1024

typedef unsigned short ushort_t;
typedef __bf16 bf16x8 __attribute__((ext_vector_type(8)));
typedef unsigned short u16x8 __attribute__((ext_vector_type(8)));
typedef float f32x4 __attribute__((ext_vector_type(4)));

__device__ __forceinline__ unsigned short f2bf(float f) {
  union { float fl; unsigned int i; } v; v.fl = f;
  return (unsigned short)((v.i + 0x7fffu + ((v.i >> 16) & 1u)) >> 16);
}

__device__ __forceinline__ void gload_lds16(const ushort_t* g, ushort_t* l) {
  __builtin_amdgcn_global_load_lds(
      (const __attribute__((address_space(1))) void*)g,
      (__attribute__((address_space(3))) void*)l, 16, 0, 0);
}

// ---------------------------------------------------------------------------
// K-PREP: one kernel, block-range partitioned.  (unchanged)
__global__ __launch_bounds__(256) void k_prep(
    const float* __restrict__ x, const float* __restrict__ mixer,
    const float* __restrict__ weight, const float* __restrict__ wb,
    const float* __restrict__ fw, float* __restrict__ e1, float* __restrict__ e2,
    ushort_t* __restrict__ fwbf, ushort_t* __restrict__ xT,
    float* __restrict__ sumb) {
  int blk = blockIdx.x;
  int t = threadIdx.x;
  if (blk < 128) {
    __shared__ float s1[G_], s2[G_];
    __shared__ float cred[2][4];
    int bp = blk >> 2;
    int nc = blk & 3;
    int b = bp >> 2, p = bp & (P_ - 1);
    int n = nc * 256 + t;
    float acc1 = 0.f, acc2 = 0.f;
    const float* wp = weight + (size_t)p * F_ * G_ + t;
    const float* mp = mixer + p * 2 * F_;
    for (int f = 0; f < F_; ++f) {
      float wv = wp[(size_t)f * G_];
      acc1 = fmaf(mp[f], wv, acc1);
      acc2 = fmaf(mp[F_ + f], wv, acc2);
    }
    s1[t] = acc1;
    s2[t] = acc2;
    float c1p = mp[t] * wb[p * F_ + t];
    float c2p = mp[F_ + t] * wb[p * F_ + t];
#pragma unroll
    for (int mask = 1; mask < 64; mask <<= 1) {
      c1p += __shfl_xor(c1p, mask, 64);
      c2p += __shfl_xor(c2p, mask, 64);
    }
    if ((t & 63) == 0) {
      cred[0][t >> 6] = c1p;
      cred[1][t >> 6] = c2p;
    }
    __syncthreads();
    float c1 = cred[0][0] + cred[0][1] + cred[0][2] + cred[0][3];
    float c2 = cred[1][0] + cred[1][1] + cred[1][2] + cred[1][3];
    const float* xb = x + (size_t)b * G_ * N_ + n;
    float a1 = 0.f, a2 = 0.f;
#pragma unroll 8
    for (int g = 0; g < G_; ++g) {
      float xv = xb[(size_t)g * N_];
      a1 = fmaf(s1[g], xv, a1);
      a2 = fmaf(s2[g], xv, a2);
    }
    e1[(size_t)bp * N_ + n] = c1 + a1;
    e2[(size_t)bp * N_ + n] = c2 + a2;
  } else if (blk < 128 + 1024) {
    int i = (blk - 128) * 1024 + t * 4;
    float4 v = *(const float4*)&fw[i];
    ushort4 o;
    o.x = f2bf(v.x); o.y = f2bf(v.y); o.z = f2bf(v.z); o.w = f2bf(v.w);
    *(ushort4*)&fwbf[i] = o;
  } else if (blk < 1152 + 512) {
    __shared__ ushort_t tile[64][66];
    int idx = blk - 1152;
    int n0 = (idx & 15) * 64;
    int g0 = ((idx >> 4) & 3) * 64;
    int b = idx >> 6;
    int rr = t >> 4, cc = (t & 15) * 4;
#pragma unroll
    for (int ps = 0; ps < 4; ++ps) {
      float4 v = *(const float4*)&x[((size_t)b * G_ + g0 + ps * 16 + rr) * N_ + n0 + cc];
      tile[ps * 16 + rr][cc] = f2bf(v.x);
      tile[ps * 16 + rr][cc + 1] = f2bf(v.y);
      tile[ps * 16 + rr][cc + 2] = f2bf(v.z);
      tile[ps * 16 + rr][cc + 3] = f2bf(v.w);
    }
    __syncthreads();
#pragma unroll
    for (int ps = 0; ps < 4; ++ps) {
      int nl = ps * 16 + rr;
      int gl = cc;
      ushort4 o;
      o.x = tile[gl][nl];
      o.y = tile[gl + 1][nl];
      o.z = tile[gl + 2][nl];
      o.w = tile[gl + 3][nl];
      *(ushort4*)&xT[((size_t)b * N_ + n0 + nl) * G_ + g0 + gl] = o;
    }
  } else {
    int i = (blk - 1664) * 256 + t;
    sumb[i] = 0.f;
  }
}

// ---------------------------------------------------------------------------
// K5: attention, UNNORMALIZED.  (unchanged)
__global__ __launch_bounds__(256) void k_att(const float* __restrict__ e1,
                                             const float* __restrict__ e2,
                                             const float* __restrict__ S,
                                             ushort_t* __restrict__ expT,
                                             float* __restrict__ sumb) {
  __shared__ ushort_t tile[256][72];   // [j-local][i-local]
  __shared__ float se1[256];
  __shared__ float se2[64];
  int bp = blockIdx.z;
  int b = bp >> 2;
  int i0 = blockIdx.y * 64;
  int jt = blockIdx.x;
  int j0 = jt * 256;
  int t = threadIdx.x;
  int rr = t >> 4;
  int cc4 = t & 15;
  int cc = cc4 * 4;

  se1[t] = e1[(size_t)bp * N_ + j0 + t];
  if (t < 64) se2[t] = e2[(size_t)bp * N_ + i0 + t];
  __syncthreads();

  const float* Sb = S + (size_t)b * N_ * N_;
  float re2[4];
#pragma unroll
  for (int ps = 0; ps < 4; ++ps) re2[ps] = se2[ps * 16 + rr];
  float psum[4] = {0.f, 0.f, 0.f, 0.f};
#pragma unroll
  for (int js = 0; js < 4; ++js) {
    float4 e1q = *(float4*)&se1[js * 64 + cc];
    float e1v[4] = {e1q.x, e1q.y, e1q.z, e1q.w};
#pragma unroll
    for (int ps = 0; ps < 4; ++ps) {
      int il = ps * 16 + rr;
      float4 s4 = *(const float4*)&Sb[(size_t)(i0 + il) * N_ + j0 + js * 64 + cc];
      float sv[4] = {s4.x, s4.y, s4.z, s4.w};
#pragma unroll
      for (int s = 0; s < 4; ++s) {
        float v = e1v[s] + re2[ps];
        float l = v >= 0.f ? v : 0.2f * v;
        bool m = fabsf(sv[s]) > 1e-9f;
        float e = m ? __expf(l) : 0.f;
        psum[ps] += e;
        tile[js * 64 + cc + s][il] = f2bf(e);
      }
    }
  }
#pragma unroll
  for (int mask = 1; mask < 16; mask <<= 1) {
#pragma unroll
    for (int ps = 0; ps < 4; ++ps) psum[ps] += __shfl_xor(psum[ps], mask, 64);
  }
  if (cc4 == 0) {
#pragma unroll
    for (int ps = 0; ps < 4; ++ps)
      atomicAdd(&sumb[(size_t)bp * N_ + i0 + ps * 16 + rr], psum[ps]);
  }
  __syncthreads();
  ushort_t* Tb = expT + (size_t)bp * N_ * N_;
  int jl0 = t >> 3;         // 0..31
  int ig = (t & 7) * 8;     // 0..56
#pragma unroll
  for (int pass = 0; pass < 8; ++pass) {
    int jl = pass * 32 + jl0;
    u16x8 v = *(const u16x8*)&tile[jl][ig];
    *(u16x8*)&Tb[(size_t)(j0 + jl) * N_ + i0 + ig] = v;
  }
}

// ---------------------------------------------------------------------------
// K6 v2: Horner step GEMM, T3-minimum 2-phase pipeline.
//   - double-buffered LDS (64 KB), prefetch tile it+1 while computing tile it
//   - raw s_barrier + counted s_waitcnt vmcnt(8): prefetch loads stay in
//     flight across the barrier (never drain vmcnt to 0 in the main loop)
//   - 1D grid + XCD-aware swizzle: all 16 blocks of one bp land on one XCD
//     (id&7 == xcd heuristic), keeping that bp's A-panel + expT slices in its
//     private 4 MB L2.
__global__ __launch_bounds__(256, 2) void gemm_step(
    const ushort_t* __restrict__ Aprev, const ushort_t* __restrict__ Bt,
    const ushort_t* __restrict__ fwbf, const ushort_t* __restrict__ xT,
    const float* __restrict__ bias, const float* __restrict__ sumb,
    ushort_t* __restrict__ outb, float* __restrict__ outf,
    int kslice, int has_prev, int last) {
  __shared__ ushort_t As[2][2][128 * 32];   // [buf][k-half][row*32+col]
  __shared__ ushort_t Bs[2][2][128 * 32];
  // ---- XCD-aware decode: id&7 = xcd, 4 bps per XCD, 16 blocks per bp ----
  int id = blockIdx.x;
  int xcd = id & 7;
  int slot = id >> 3;            // 0..63
  int bp = xcd * 4 + (slot >> 4);
  int inner = slot & 15;
  int m0 = (inner >> 3) * 128;   // 0..128
  int n0 = (inner & 7) * 128;    // 0..896
  int p = bp & (P_ - 1), b = bp >> 2;
  int t = threadIdx.x;
  int lane = t & 63;
  int w = t >> 6;
  int wm = w >> 1, wn = w & 1;
  int lr = lane & 15, quad = lane >> 4;
  int rowL = t >> 2;            // 0..63
  int colL = (t & 3) * 8;       // 0,8,16,24
  int ldsoff = (t & ~63) * 8;   // wave-uniform LDS base (ushort units)

  const ushort_t* A1 = has_prev
      ? Aprev + (size_t)bp * (F_ * N_) + (size_t)(m0 + rowL) * N_ + colL
      : (const ushort_t*)nullptr;
  const ushort_t* B1 = Bt + (size_t)bp * N_ * N_ + (size_t)(n0 + rowL) * N_ + colL;
  const ushort_t* A2 = fwbf + (size_t)p * (F_ * KG_) + (size_t)(m0 + rowL) * KG_ +
                       kslice * G_ + colL;
  const ushort_t* B2 = xT + (size_t)b * (N_ * G_) + (size_t)(n0 + rowL) * G_ + colL;

  const int ntA = has_prev ? (N_ / 64) : 0;   // 16 or 0
  const int NT = ntA + G_ / 64;               // 20 or 4

  f32x4 acc[4][4] = {};

  auto stage = [&](int buf, int it) {
    const ushort_t *Ab, *Bb;
    size_t ldA, ldB;
    int ko;
    if (it < ntA) {
      Ab = A1; ldA = N_; Bb = B1; ldB = N_; ko = it * 64;
    } else {
      Ab = A2; ldA = KG_; Bb = B2; ldB = G_; ko = (it - ntA) * 64;
    }
    gload_lds16(Ab + ko,                 &As[buf][0][ldsoff]);
    gload_lds16(Ab + 64 * ldA + ko,      &As[buf][0][2048 + ldsoff]);
    gload_lds16(Ab + ko + 32,            &As[buf][1][ldsoff]);
    gload_lds16(Ab + 64 * ldA + ko + 32, &As[buf][1][2048 + ldsoff]);
    gload_lds16(Bb + ko,                 &Bs[buf][0][ldsoff]);
    gload_lds16(Bb + 64 * ldB + ko,      &Bs[buf][0][2048 + ldsoff]);
    gload_lds16(Bb + ko + 32,            &Bs[buf][1][ldsoff]);
    gload_lds16(Bb + 64 * ldB + ko + 32, &Bs[buf][1][2048 + ldsoff]);
  };

  // prologue: stage tile 0 into buf 0
  stage(0, 0);
  int buf = 0;
  for (int it = 0; it < NT; ++it) {
    if (it + 1 < NT) {
      stage(buf ^ 1, it + 1);                          // 8 loads in flight
      asm volatile("s_waitcnt vmcnt(8)" ::: "memory"); // cur tile landed
    } else {
      asm volatile("s_waitcnt vmcnt(0)" ::: "memory");
    }
    __builtin_amdgcn_s_barrier();        // all waves' cur-tile DMA visible
    asm volatile("" ::: "memory");
#pragma unroll
    for (int c = 0; c < 2; ++c) {
      bf16x8 af[4], bfr[4];
#pragma unroll
      for (int mi = 0; mi < 4; ++mi)
        af[mi] = __builtin_bit_cast(bf16x8,
            *(const u16x8*)&As[buf][c][(wm * 64 + mi * 16 + lr) * 32 + quad * 8]);
#pragma unroll
      for (int ni = 0; ni < 4; ++ni)
        bfr[ni] = __builtin_bit_cast(bf16x8,
            *(const u16x8*)&Bs[buf][c][(wn * 64 + ni * 16 + lr) * 32 + quad * 8]);
#pragma unroll
      for (int mi = 0; mi < 4; ++mi)
#pragma unroll
        for (int ni = 0; ni < 4; ++ni)
          acc[mi][ni] = __builtin_amdgcn_mfma_f32_16x16x32_bf16(af[mi], bfr[ni], acc[mi][ni], 0, 0, 0);
    }
    asm volatile("" ::: "memory");
    __builtin_amdgcn_s_barrier();        // reads done before buf overwritten
    buf ^= 1;
  }

  if (last) {
    float* Ob = outf + (size_t)bp * (F_ * N_);
#pragma unroll
    for (int mi = 0; mi < 4; ++mi) {
      int fbase = m0 + wm * 64 + mi * 16 + quad * 4;
#pragma unroll
      for (int ni = 0; ni < 4; ++ni) {
        int n = n0 + wn * 64 + ni * 16 + lr;
#pragma unroll
        for (int r = 0; r < 4; ++r) {
          float v = acc[mi][ni][r] + bias[fbase + r];
          Ob[(size_t)(fbase + r) * N_ + n] = v >= 0.f ? v : 0.01f * v;
        }
      }
    }
  } else {
    ushort_t* Ob = outb + (size_t)bp * (F_ * N_);
    float iv[4];
#pragma unroll
    for (int ni = 0; ni < 4; ++ni)
      iv[ni] = 1.0f / sumb[(size_t)bp * N_ + n0 + wn * 64 + ni * 16 + lr];
#pragma unroll
    for (int mi = 0; mi < 4; ++mi) {
      int fbase = m0 + wm * 64 + mi * 16 + quad * 4;
#pragma unroll
      for (int ni = 0; ni < 4; ++ni) {
        int n = n0 + wn * 64 + ni * 16 + lr;
#pragma unroll
        for (int r = 0; r < 4; ++r)
          Ob[(size_t)(fbase + r) * N_ + n] = f2bf(acc[mi][ni][r] * iv[ni]);
      }
    }
  }
}

// ---------------------------------------------------------------------------
extern "C" void kernel_launch(void* const* d_in, const int* in_sizes, int n_in,
                              void* d_out, int out_size, void* d_ws, size_t ws_size,
                              hipStream_t stream) {
  const float* x = (const float*)d_in[0];
  const float* mixer = (const float*)d_in[1];
  const float* weight = (const float*)d_in[2];
  const float* wb = (const float*)d_in[3];
  const float* fw = (const float*)d_in[4];
  const float* bias = (const float*)d_in[5];
  const float* S = (const float*)d_in[6];
  float* out = (float*)d_out;

  char* ws = (char*)d_ws;
  size_t off = 0;
  auto take = [&](size_t bytes) -> char* {
    char* p = ws + off;
    off = (off + bytes + 255) & ~(size_t)255;
    return p;
  };
  float* e1 = (float*)take((size_t)B_ * P_ * N_ * 4);
  float* e2 = (float*)take((size_t)B_ * P_ * N_ * 4);
  float* sumb = (float*)take((size_t)B_ * P_ * N_ * 4);
  ushort_t* fwbf = (ushort_t*)take((size_t)P_ * F_ * KHOP * G_ * 2);
  ushort_t* xT = (ushort_t*)take((size_t)B_ * N_ * G_ * 2);
  ushort_t* expT = (ushort_t*)take((size_t)B_ * P_ * N_ * N_ * 2);
  ushort_t* sA = (ushort_t*)take((size_t)B_ * P_ * F_ * N_ * 2);
  ushort_t* sB = (ushort_t*)take((size_t)B_ * P_ * F_ * N_ * 2);

  k_prep<<<1792, 256, 0, stream>>>(x, mixer, weight, wb, fw, e1, e2, fwbf, xT, sumb);
  k_att<<<dim3(4, 16, 32), 256, 0, stream>>>(e1, e2, S, expT, sumb);

  // Horner (1/rowsum folded into stored intermediates):
  // s3' = (fw3*x) . inv ; s2' = (s3'*E^T + fw2*x) . inv ;
  // s1' = (s2'*E^T + fw1*x) . inv ; out = lrelu(s1'*E^T + fw0*x + bias)
  gemm_step<<<512, 256, 0, stream>>>(nullptr, expT, fwbf, xT, bias, sumb, sA, nullptr, 3, 0, 0);
  gemm_step<<<512, 256, 0, stream>>>(sA, expT, fwbf, xT, bias, sumb, sB, nullptr, 2, 1, 0);
  gemm_step<<<512, 256, 0, stream>>>(sB, expT, fwbf, xT, bias, sumb, sA, nullptr, 1, 1, 0);
  gemm_step<<<512, 256, 0, stream>>>(sA, expT, fwbf, xT, bias, sumb, nullptr, out, 0, 1, 1);
}